// Round 3
// baseline (270.715 us; speedup 1.0000x reference)
//
#include <hip/hip_runtime.h>
#include <math.h>

typedef float f32x4 __attribute__((ext_vector_type(4)));

// Problem constants
#define B_     16
#define C_     32
#define D_     2
#define HW_    4096               // 64*64
#define NPIX   (B_ * D_ * HW_)    // 131072 pixels
#define NPAIRP 576                // pairs padded: row c has rlen(c) = 4*(c/4+1) slots
#define NROWSP 592                // +16 zero rows so pipeline prefetch stays in bounds

// ---------------------------------------------------------------------------
// Prep: fold weight [O=32,C=32,C=32] into padded symmetric pair table
//   wpad[kp][o]. Row c starts at kpbase(c) = 4*(c + 2a(a-1) + a*b), a=c>>2, b=c&3.
//   Slot j in [0,rlen): j<=c -> W[o,c,j]+W[o,j,c] (diag once), else 0.
// One thread per (c, j, o); extra range zero-fills rows [576,592).
// ---------------------------------------------------------------------------
__global__ void prep_wsym(const float* __restrict__ w, float* __restrict__ wpad) {
    int idx = blockIdx.x * blockDim.x + threadIdx.x;
    const int total1 = 32 * 32 * 32;
    const int totalz = (NROWSP - NPAIRP) * 32;
    if (idx < total1) {
        int o = idx & 31;
        int j = (idx >> 5) & 31;
        int c = idx >> 10;
        int a = c >> 2, b = c & 3;
        int rlen = (a + 1) << 2;
        if (j >= rlen) return;                    // slot belongs to another row
        int kb = 4 * (c + 2 * a * (a - 1) + a * b);
        float v = 0.0f;
        if (j <= c) {
            const float* wo = w + o * (C_ * C_);
            v = (j == c) ? wo[c * C_ + c] : (wo[c * C_ + j] + wo[j * C_ + c]);
        }
        wpad[(kb + j) * 32 + o] = v;
    } else if (idx < total1 + totalz) {
        wpad[NPAIRP * 32 + (idx - total1)] = 0.0f;
    }
}

// ---------------------------------------------------------------------------
// Main kernel. Block = 128 threads = 2 waves over the SAME 64 pixels;
// wave 0 computes outputs o in [0,16), wave 1 o in [16,32)  ->  32 acc VGPRs.
// cos/sin staged in XOR-swizzled LDS (ds_read_b128 conflict-free).
// Weights streamed as vector global_load_dwordx4 (opaque-zero VGPR offset
// prevents scalarization -> vmcnt pipe, compiler-counted waits), software-
// pipelined 4 pairs deep in plain C.
// ---------------------------------------------------------------------------
#define TPB 128

#define FMA4R(Wq, qb) do { \
    accr[qb+0] = fmaf((Wq)[0], ur_, accr[qb+0]); \
    accr[qb+1] = fmaf((Wq)[1], ur_, accr[qb+1]); \
    accr[qb+2] = fmaf((Wq)[2], ur_, accr[qb+2]); \
    accr[qb+3] = fmaf((Wq)[3], ur_, accr[qb+3]); \
    acci[qb+0] = fmaf((Wq)[0], ui_, acci[qb+0]); \
    acci[qb+1] = fmaf((Wq)[1], ui_, acci[qb+1]); \
    acci[qb+2] = fmaf((Wq)[2], ui_, acci[qb+2]); \
    acci[qb+3] = fmaf((Wq)[3], ui_, acci[qb+3]); \
} while (0)

#define PAIR(W0, W1, W2, W3, cve, sve) do { \
    float ur_ = cvc * (cve) - svc * (sve); \
    float ui_ = fmaf(cvc, (sve), svc * (cve)); \
    FMA4R(W0, 0); FMA4R(W1, 4); FMA4R(W2, 8); FMA4R(W3, 12); \
} while (0)

// Load this wave's 16-float half of pair row kp_ into 4 named f32x4 regs.
#define LOADW(Wb, kp_) do { \
    const f32x4* p_ = (const f32x4*)(wp + (size_t)(kp_) * 128); \
    Wb##0 = p_[0]; Wb##1 = p_[1]; Wb##2 = p_[2]; Wb##3 = p_[3]; \
} while (0)

__global__ __launch_bounds__(TPB, 3) void bilinear_kernel(
    const float* __restrict__ x,
    const float* __restrict__ wpad,
    const float* __restrict__ bias,
    float* __restrict__ out)
{
    __shared__ float ldsc[64 * 32];   // [pixel][channel^swz], 8 KB
    __shared__ float ldss[64 * 32];   // 8 KB

    const int l  = threadIdx.x & 63;        // pixel lane
    const int wv = threadIdx.x >> 6;        // o-half (0/1)
    const int P0 = blockIdx.x * 64;
    const int b  = P0 >> 13;
    const int d  = (P0 >> 12) & 1;
    const int hw = (P0 & 4095) + l;
    const int base = b * (C_ * D_ * HW_) + d * HW_ + hw;   // channel stride D_*HW_

    const int swz = (l & 7) << 2;
    float* slc = ldsc + l * 32;
    float* sls = ldss + l * 32;

    // Stage cos/sin: each wave does 16 channels for its own pixel lane.
    #pragma unroll
    for (int cc = 0; cc < 16; ++cc) {
        int c = wv * 16 + cc;
        float xv = x[base + c * (D_ * HW_)];
        float s, co;
        __sincosf(xv, &s, &co);
        slc[c ^ swz] = co;
        sls[c ^ swz] = s;
    }
    __syncthreads();

    float accr[16], acci[16];
    #pragma unroll
    for (int o = 0; o < 16; ++o) { accr[o] = 0.0f; acci[o] = 0.0f; }

    // Opaque zero in a VGPR: compiler cannot prove the weight address is
    // wave-uniform -> keeps vector global_load_dwordx4 (vmcnt pipe).
    int zero_;
    asm volatile("v_mov_b32 %0, 0" : "=v"(zero_));
    const char* wp = (const char*)wpad + zero_ + wv * 64;  // our 64 B half-row

    f32x4 wA0, wA1, wA2, wA3, wB0, wB1, wB2, wB3;
    f32x4 wC0, wC1, wC2, wC3, wD0, wD1, wD2, wD3;
    LOADW(wA, 0); LOADW(wB, 1); LOADW(wC, 2); LOADW(wD, 3);

    int c = 0, e0 = 0, kp = 0;
    float cvc, svc;
    #pragma unroll 1
    for (int gi = 0; gi < 144; ++gi) {
        cvc = slc[c ^ swz];
        svc = sls[c ^ swz];
        const f32x4 ce = *(const f32x4*)(slc + (e0 ^ swz));
        const f32x4 se = *(const f32x4*)(sls + (e0 ^ swz));
        PAIR(wA0, wA1, wA2, wA3, ce[0], se[0]); LOADW(wA, kp + 4);
        PAIR(wB0, wB1, wB2, wB3, ce[1], se[1]); LOADW(wB, kp + 5);
        PAIR(wC0, wC1, wC2, wC3, ce[2], se[2]); LOADW(wC, kp + 6);
        PAIR(wD0, wD1, wD2, wD3, ce[3], se[3]); LOADW(wD, kp + 7);
        kp += 4;
        e0 += 4;
        if (e0 > c) { e0 = 0; ++c; }    // uniform scalar control
    }

    #pragma unroll
    for (int oo = 0; oo < 16; ++oo) {
        int o = wv * 16 + oo;
        out[base + o * (D_ * HW_)] = atan2f(acci[oo], accr[oo]) + bias[o];
    }
}

// ---------------------------------------------------------------------------
extern "C" void kernel_launch(void* const* d_in, const int* in_sizes, int n_in,
                              void* d_out, int out_size, void* d_ws, size_t ws_size,
                              hipStream_t stream) {
    const float* x    = (const float*)d_in[0];
    const float* w    = (const float*)d_in[1];
    const float* bias = (const float*)d_in[2];
    float* out        = (float*)d_out;
    float* wpad       = (float*)d_ws;   // needs NROWSP*32*4 = 75,776 B

    {
        int n = 32 * 32 * 32 + (NROWSP - NPAIRP) * 32;
        int tpb = 256;
        prep_wsym<<<(n + tpb - 1) / tpb, tpb, 0, stream>>>(w, wpad);
    }
    {
        int grid = NPIX / 64;   // 2048 blocks, 2 waves each
        bilinear_kernel<<<grid, TPB, 0, stream>>>(x, wpad, bias, out);
    }
}

// Round 4
// 115.944 us; speedup vs baseline: 2.3349x; 2.3349x over previous
//
#include <hip/hip_runtime.h>
#include <math.h>

// Problem constants
#define B_     16
#define C_     32
#define D_     2
#define HW_    4096               // 64*64
#define NPIX   (B_ * D_ * HW_)    // 131072 pixels
#define NPAIRP 576                // padded pair slots: row c has rlen(c)=4*(c/4+1)
#define NROWSP 592                // + zero rows (margin; not read by main kernel)

// ---------------------------------------------------------------------------
// Prep (verified in R2: absmax matches R0): fold weight [O,C,C] into padded
// symmetric pair table wpad[kp][o]. Row c starts at kpbase(c)=4*(c+2a(a-1)+ab),
// a=c>>2, b=c&3. Slot j<=c: W[o,c,j]+W[o,j,c] (diag once); pad slots = 0.
// ---------------------------------------------------------------------------
__global__ void prep_wsym(const float* __restrict__ w, float* __restrict__ wpad) {
    int idx = blockIdx.x * blockDim.x + threadIdx.x;
    const int total1 = 32 * 32 * 32;
    const int totalz = (NROWSP - NPAIRP) * 32;
    if (idx < total1) {
        int o = idx & 31;
        int j = (idx >> 5) & 31;
        int c = idx >> 10;
        int a = c >> 2, b = c & 3;
        int rlen = (a + 1) << 2;
        if (j >= rlen) return;
        int kb = 4 * (c + 2 * a * (a - 1) + a * b);
        float v = 0.0f;
        if (j <= c) {
            const float* wo = w + o * (C_ * C_);
            v = (j == c) ? wo[c * C_ + c] : (wo[c * C_ + j] + wo[j * C_ + c]);
        }
        wpad[(kb + j) * 32 + o] = v;
    } else if (idx < total1 + totalz) {
        wpad[NPAIRP * 32 + (idx - total1)] = 0.0f;
    }
}

// ---------------------------------------------------------------------------
// Main kernel. Block = 128 threads = 2 waves over the SAME 128 pixels.
// Wave wv computes outputs [wv*16, wv*16+16) for all 128 pixels
// (T=2 pixels per lane: pa=l, pb=l+64)  ->  64 acc VGPRs.
//
// Trig staged TRANSPOSED in LDS: trig[c][cos|sin][128] -> every read is
// lane-stride-1 (2 lanes/bank, conflict-free).
//
// e-register blocking: eb = static block of 4 e-values held in 16 named
// VGPRs. Inner c-loop: 4 pair-slots/iter = 288 VALU inst (576 cyc) per
// {4 ds_read + 4 s_load_dwordx16} -> lgkm drains amortized 4x vs R0.
// Weights stay wave-uniform (readfirstlane on wv) -> SMEM, zero VMEM.
// ---------------------------------------------------------------------------
#define TPB 128

__global__ __launch_bounds__(TPB, 2) void bilinear_kernel(
    const float* __restrict__ x,
    const float* __restrict__ wpad,
    const float* __restrict__ bias,
    float* __restrict__ out)
{
    __shared__ float trig[C_][2][128];   // 32 KB

    const int l    = threadIdx.x & 63;
    const int wv   = __builtin_amdgcn_readfirstlane(threadIdx.x >> 6);  // o-half
    const int P0   = blockIdx.x * 128;           // first pixel of block
    const int b    = P0 >> 13;
    const int d    = (P0 >> 12) & 1;
    const int hw0  = P0 & 4095;                  // 128-aligned, block stays in (b,d)
    const int pixbase = b * (C_ * D_ * HW_) + d * HW_ + hw0;  // + pix + c*8192

    // ---- prologue: stage cos/sin for my pixel (mypix = l + wv*64) ----
    const int mypix = l + (wv << 6);
    #pragma unroll 4
    for (int c = 0; c < C_; ++c) {
        float xv = x[pixbase + mypix + c * (D_ * HW_)];
        float s, co;
        __sincosf(xv, &s, &co);
        trig[c][0][mypix] = co;
        trig[c][1][mypix] = s;
    }
    __syncthreads();

    float accr0[16], acci0[16], accr1[16], acci1[16];
    #pragma unroll
    for (int q = 0; q < 16; ++q) { accr0[q] = 0.f; acci0[q] = 0.f; accr1[q] = 0.f; acci1[q] = 0.f; }

    const int pa = l, pb = l + 64;
    const float* __restrict__ wbase = wpad + wv * 16;   // our o-half of each 32-float row

    #pragma unroll 1
    for (int eb = 0; eb < 8; ++eb) {
        const int e0 = eb << 2;
        // 16 trig registers for this e-block (static names via unrolled arrays)
        float cea[4], sea[4], ceb[4], seb[4];
        #pragma unroll
        for (int j = 0; j < 4; ++j) {
            cea[j] = trig[e0 + j][0][pa];
            sea[j] = trig[e0 + j][1][pa];
            ceb[j] = trig[e0 + j][0][pb];
            seb[j] = trig[e0 + j][1][pb];
        }
        int kpb = 8 * eb * (eb + 1);   // kpbase(4*eb)
        #pragma unroll 1
        for (int c = e0; c < C_; ++c) {
            const float cva = trig[c][0][pa];
            const float sva = trig[c][1][pa];
            const float cvb = trig[c][0][pb];
            const float svb = trig[c][1][pb];
            const float* __restrict__ wr = wbase + (kpb + e0) * 32;  // uniform -> s_load
            #pragma unroll
            for (int p = 0; p < 4; ++p) {
                float ura = fmaf(cva, cea[p], -(sva * sea[p]));
                float uia = fmaf(cva, sea[p],   sva * cea[p]);
                float urb = fmaf(cvb, ceb[p], -(svb * seb[p]));
                float uib = fmaf(cvb, seb[p],   svb * ceb[p]);
                #pragma unroll
                for (int q = 0; q < 16; ++q) {
                    const float wq = wr[p * 32 + q];
                    accr0[q] = fmaf(wq, ura, accr0[q]);
                    acci0[q] = fmaf(wq, uia, acci0[q]);
                    accr1[q] = fmaf(wq, urb, accr1[q]);
                    acci1[q] = fmaf(wq, uib, acci1[q]);
                }
            }
            kpb += ((c >> 2) + 1) << 2;   // += rowlen(c)
        }
    }

    // ---- epilogue: angle + bias, coalesced stores ----
    #pragma unroll
    for (int q = 0; q < 16; ++q) {
        const int o = wv * 16 + q;
        const float bo = bias[o];
        out[pixbase + pa + o * (D_ * HW_)] = atan2f(acci0[q], accr0[q]) + bo;
        out[pixbase + pb + o * (D_ * HW_)] = atan2f(acci1[q], accr1[q]) + bo;
    }
}

// ---------------------------------------------------------------------------
extern "C" void kernel_launch(void* const* d_in, const int* in_sizes, int n_in,
                              void* d_out, int out_size, void* d_ws, size_t ws_size,
                              hipStream_t stream) {
    const float* x    = (const float*)d_in[0];
    const float* w    = (const float*)d_in[1];
    const float* bias = (const float*)d_in[2];
    float* out        = (float*)d_out;
    float* wpad       = (float*)d_ws;   // needs NROWSP*32*4 = 75,776 B

    {
        int n = 32 * 32 * 32 + (NROWSP - NPAIRP) * 32;
        int tpb = 256;
        prep_wsym<<<(n + tpb - 1) / tpb, tpb, 0, stream>>>(w, wpad);
    }
    {
        int grid = NPIX / 128;   // 1024 blocks, 2 waves each
        bilinear_kernel<<<grid, TPB, 0, stream>>>(x, wpad, bias, out);
    }
}